// Round 16
// baseline (242.134 us; speedup 1.0000x reference)
//
#include <hip/hip_runtime.h>
#include <math.h>

// infoFSM mask-scorer MLP — Round 15: 4-independent-blocks/CU main (NT=256).
//
// R14 post-mortem (NULL): TM=64 halved weight-L2, no spill, yet main
// 167->175us. Sum-of-terms model refuted; with MFMA 13%, VALU 29%, HBM 10%,
// L2 non-binding, ~55% of main is PHASE-SERIALIZATION stall behind 7
// block-wide barriers with only 2 independent blocks/CU. R15: NT 512->256,
// TM=32 -> same per-CU resources but 4 INDEPENDENT blocks/CU (4 waves/SIMD
// each at a different phase; barriers sync 4 waves not 8). Per-thread work
// x2 (4 G1 n-tiles / 2 G2 / 2x2 G3 per wave), aggregate identical.
// Single-chain accumulation per n-tile (order delta << 22sigma band; in-band
// rows recomputed exactly by fix pass -> absmax stays 0).
// Also: ctr memset folded into prep (-1 launch). prep/fix = R13 proven.

namespace {

constexpr int R_ROWS = 128 * 512;   // 65536
constexpr int D0 = 512, D1 = 512, D2 = 256, D3 = 128;
constexpr int TM = 32;              // rows per block (pass B)
constexpr int NT = 256;             // 4 waves

typedef _Float16 vhalf8 __attribute__((ext_vector_type(8)));
typedef _Float16 vhalf4 __attribute__((ext_vector_type(4)));
typedef __attribute__((ext_vector_type(16))) float vf16;
typedef __attribute__((ext_vector_type(4)))  float vf4;

// ---------------- helpers ----------------
__device__ __forceinline__ float gelu_exact(float x) {
    return 0.5f * x * (1.0f + erff(x * 0.70710678118654752440f));
}
// A&S 7.1.26 erf: |abs err| <= 1.5e-7 — far below fp16 path error.
__device__ __forceinline__ float gelu_fast(float x) {
    const float s = fabsf(x) * 0.70710678118654752440f;
    const float t = __builtin_amdgcn_rcpf(fmaf(0.3275911f, s, 1.0f));
    float p = fmaf(1.061405429f, t, -1.453152027f);
    p = fmaf(p, t, 1.421413741f);
    p = fmaf(p, t, -0.284496736f);
    p = fmaf(p, t, 0.254829592f);
    p *= t;
    const float e = __builtin_amdgcn_exp2f(s * s * -1.44269504088896341f);
    float er = fmaf(-p, e, 1.0f);             // erf(|x|/sqrt2)
    er = copysignf(er, x);
    return 0.5f * x * (1.0f + er);
}
__device__ __forceinline__ vf16 vzero16() {
    vf16 v;
    #pragma unroll
    for (int i = 0; i < 16; ++i) v[i] = 0.0f;
    return v;
}
__device__ __forceinline__ vf4 vzero4() {
    vf4 v;
    #pragma unroll
    for (int i = 0; i < 4; ++i) v[i] = 0.0f;
    return v;
}

// LDS activation tiles: [row][k] fp16, XOR-swizzle bits 4..6.
__device__ __forceinline__ int swz_off(int row, int colElem, int pitchB) {
    return (row * pitchB + colElem * 2) ^ ((row & 7) << 4);
}
// 32x32 A-fragment read: row = lane&31, k = k0 + (lane>>5)*8
__device__ __forceinline__ vhalf8 ld_act32(const char* base, int lane, int pitchB,
                                           int k0) {
    const int row = lane & 31;
    const int k = k0 + ((lane >> 5) << 3);
    return *(const vhalf8*)(base + swz_off(row, k, pitchB));
}
// 16x16 A-fragment read: row = row0 + lane&15, k = k0 + (lane>>4)*8
__device__ __forceinline__ vhalf8 ld_act16(const char* base, int lane, int pitchB,
                                           int row0, int k0) {
    const int row = row0 + (lane & 15);
    const int k = k0 + ((lane >> 4) << 3);
    return *(const vhalf8*)(base + swz_off(row, k, pitchB));
}
// packed weight fragment: P + blk*1024B + lane*16B
__device__ __forceinline__ vhalf8 ld_pack(const char* __restrict__ P,
                                          int blk, int lane) {
    return *(const vhalf8*)(P + (((size_t)blk) << 10) + (lane << 4));
}
__device__ __forceinline__ void st_hi(char* base, int row, int col, int pitchB, float x) {
    *(_Float16*)(base + swz_off(row, col, pitchB)) = (_Float16)x;
}

#define MFMA32(a, b, c) __builtin_amdgcn_mfma_f32_32x32x16_f16((a), (b), (c), 0, 0, 0)
#define MFMA16(a, b, c) __builtin_amdgcn_mfma_f32_16x16x32_f16((a), (b), (c), 0, 0, 0)

constexpr float BAND = 2e-3f;   // on v = prob*prev_m; ~22x RMS fp16-path err

// ---------------- pass A: prep weights (+ctr zero; pack + transposes) -------
__global__ __launch_bounds__(256) void prep_weights(
    const float* __restrict__ W_L, const float* __restrict__ W_l1,
    const float* __restrict__ W_l2,
    char* __restrict__ P1, char* __restrict__ P2, char* __restrict__ P3,
    float* __restrict__ WT1, float* __restrict__ WT2, float* __restrict__ WT3,
    unsigned int* __restrict__ ctr)
{
    if (blockIdx.x == 0 && threadIdx.x == 0) *ctr = 0;   // replaces memset
    if (blockIdx.x < 208) {
        const int g = blockIdx.x * 256 + threadIdx.x;   // 53248 threads
        const float* src;
        char* dst;
        int e, k, K, blk, lane;
        if (g < 32768) {
            lane = g & 63;
            const int ks = (g >> 6) & 31, nt = g >> 11;
            src = W_L; K = 512; dst = P1;
            e = nt * 32 + (lane & 31);
            k = ks * 16 + ((lane >> 5) << 3);
            blk = nt * 32 + ks;
        } else if (g < 49152) {
            const int h = g - 32768;
            lane = h & 63;
            const int ks = (h >> 6) & 31, nt = h >> 11;
            src = W_l1; K = 512; dst = P2;
            e = nt * 32 + (lane & 31);
            k = ks * 16 + ((lane >> 5) << 3);
            blk = nt * 32 + ks;
        } else {
            const int h = g - 49152;
            lane = h & 63;
            const int ks = (h >> 6) & 7, nt = h >> 9;
            src = W_l2; K = 256; dst = P3;
            e = nt * 16 + (lane & 15);
            k = ks * 32 + ((lane >> 4) << 3);
            blk = nt * 8 + ks;
        }
        const float4 v0 = *(const float4*)&src[(size_t)e * K + k];
        const float4 v1 = *(const float4*)&src[(size_t)e * K + k + 4];
        const float xs[8] = {v0.x, v0.y, v0.z, v0.w, v1.x, v1.y, v1.z, v1.w};
        vhalf8 hv;
        #pragma unroll
        for (int j = 0; j < 8; ++j) hv[j] = (_Float16)xs[j];
        *(vhalf8*)(dst + (((size_t)blk) << 10) + lane * 16) = hv;
    } else {
        const int g = (blockIdx.x - 208) * 256 + threadIdx.x;   // 425984 threads
        if (g < 262144) {
            const int k = g >> 9, e = g & 511;
            WT1[g] = W_L[(size_t)e * 512 + k];
        } else if (g < 393216) {
            const int h = g - 262144;
            const int k = h >> 8, e = h & 255;
            WT2[h] = W_l1[(size_t)e * 512 + k];
        } else {
            const int h = g - 393216;
            const int k = h >> 7, e = h & 127;
            WT3[h] = W_l2[(size_t)e * 256 + k];
        }
    }
}

// ---------------- pass B: fused fp16 MFMA MLP, TM=32, NT=256, 33.4KB LDS ----
// LDS overlay (bytes):
//   stage A:  A  [0,32K)  f16 [32][512] pitch 1024
//   GEMM1 ep: X1 [0,32K)  f16 [32][512] pitch 1024  (A dead, B2a)
//   GEMM2 ep: X2 [0,16K)  f16 [32][256] pitch 512   (X1 dead, B3a)
//   GEMM3 ep: X3 [16K, 16K+16896) f32 [32][132]     (X1 upper dead; disjoint X2)
//   sM at [33280, 33408)
constexpr int SMEM_BYTES = 33280 + 128;

__global__ __launch_bounds__(NT, 4) void mlp_mfma(
    const float* __restrict__ input, const float* __restrict__ prev_m,
    const float* __restrict__ W_l3,
    const char* __restrict__ P1, const char* __restrict__ P2,
    const char* __restrict__ P3,
    float* __restrict__ out, float* __restrict__ mask_out, float* __restrict__ currm_out,
    unsigned int* __restrict__ ctr, int* __restrict__ list)
{
    __shared__ __attribute__((aligned(16))) char smem[SMEM_BYTES];
    char* A   = smem;                         // then X1, then X2 (overlaid)
    float* sX3 = (float*)(smem + 16384);      // [32][132] f32
    float* sM  = (float*)(smem + 33280);      // [32]

    const int tid  = threadIdx.x;
    const int lane = tid & 63;
    const int wid  = tid >> 6;                // 0..3
    const int row0 = blockIdx.x * TM;

    // ---- stage A: 32 input rows -> fp16, swizzled (16 iters @ 256 thr) ----
    #pragma unroll 4
    for (int i = 0; i < 16; ++i) {
        const int c  = i * NT + tid;           // 0..4095 float4-chunks
        const int r  = c >> 7;                 // 0..31
        const int kq = (c & 127) << 2;
        const float4 v = *(const float4*)&input[(size_t)(row0 + r) * D0 + kq];
        vhalf4 hv = {(_Float16)v.x, (_Float16)v.y, (_Float16)v.z, (_Float16)v.w};
        const int off = (r * 1024 + kq * 2) ^ ((r & 7) << 4);   // 8B-aligned
        *(vhalf4*)(A + off) = hv;
    }
    __syncthreads();   // B1: A staged

    // ---- GEMM1: X1 = gelu(A @ W_L^T), 32x512, K=512, 32x32x16 ----
    // wave owns n-tiles 4wid..4wid+3; single acc chain per n-tile (64 regs).
    vf16 g1[4];
    {
        const int nt0 = wid * 4;
        #pragma unroll
        for (int j = 0; j < 4; ++j) g1[j] = vzero16();
        #pragma unroll 1
        for (int ks = 0; ks < 32; ++ks) {
            const int k0 = ks * 16;
            vhalf8 ah = ld_act32(A, lane, 1024, k0);
            #pragma unroll
            for (int j = 0; j < 4; ++j) {
                vhalf8 b = ld_pack(P1, (nt0 + j) * 32 + ks, lane);
                g1[j] = MFMA32(ah, b, g1[j]);
            }
        }
    }
    __syncthreads();   // B2a: all waves done reading A
    {
        const int nt0 = wid * 4;
        #pragma unroll
        for (int j = 0; j < 4; ++j) {
            const int e0 = (nt0 + j) * 32 + (lane & 31);
            #pragma unroll
            for (int r = 0; r < 16; ++r) {
                const int rr = (r & 3) + 8 * (r >> 2) + 4 * (lane >> 5);
                st_hi(A, rr, e0, 1024, gelu_fast(g1[j][r]));
            }
        }
    }
    __syncthreads();   // B2b: X1 ready (in A's region)

    // ---- GEMM2: X2 = gelu(X1 @ W_l1^T), 32x256, K=512, 32x32x16 ----
    vf16 g2[2];
    {
        const int nt0 = wid * 2;
        g2[0] = vzero16(); g2[1] = vzero16();
        #pragma unroll 1
        for (int ks = 0; ks < 32; ++ks) {
            const int k0 = ks * 16;
            vhalf8 ah = ld_act32(A, lane, 1024, k0);
            #pragma unroll
            for (int j = 0; j < 2; ++j) {
                vhalf8 b = ld_pack(P2, (nt0 + j) * 32 + ks, lane);
                g2[j] = MFMA32(ah, b, g2[j]);
            }
        }
    }
    __syncthreads();   // B3a: all waves done reading X1
    {
        const int nt0 = wid * 2;
        #pragma unroll
        for (int j = 0; j < 2; ++j) {
            const int e0 = (nt0 + j) * 32 + (lane & 31);
            #pragma unroll
            for (int r = 0; r < 16; ++r) {
                const int rr = (r & 3) + 8 * (r >> 2) + 4 * (lane >> 5);
                st_hi(A, rr, e0, 512, gelu_fast(g2[j][r]));
            }
        }
    }
    __syncthreads();   // B3b: X2 ready (in [0,16K))

    // ---- GEMM3: X3 = gelu(X2 @ W_l2^T), 32x128, K=256, 16x16x32 ----
    // wave owns n-tiles 2wid,2wid+1 x m-tiles 0,1.
    {
        const int nt0 = wid * 2;
        vf4 ac00 = vzero4(), ac10 = vzero4(), ac01 = vzero4(), ac11 = vzero4();
        #pragma unroll 1
        for (int ks = 0; ks < 8; ++ks) {
            const int k0 = ks * 32;
            vhalf8 b0 = ld_pack(P3, nt0 * 8 + ks, lane);
            vhalf8 b1 = ld_pack(P3, (nt0 + 1) * 8 + ks, lane);
            vhalf8 a0 = ld_act16(A, lane, 512, 0,  k0);
            vhalf8 a1 = ld_act16(A, lane, 512, 16, k0);
            ac00 = MFMA16(a0, b0, ac00);
            ac10 = MFMA16(a1, b0, ac10);
            ac01 = MFMA16(a0, b1, ac01);
            ac11 = MFMA16(a1, b1, ac11);
        }
        // X3 at [16K,33K): disjoint from X2 [0,16K); overlays dead X1 upper.
        #pragma unroll
        for (int r = 0; r < 4; ++r) {
            const int rr = ((lane >> 4) << 2) + r;
            const int c0 = nt0 * 16 + (lane & 15);
            sX3[rr * 132 + c0]             = gelu_fast(ac00[r]);
            sX3[(rr + 16) * 132 + c0]      = gelu_fast(ac10[r]);
            sX3[rr * 132 + c0 + 16]        = gelu_fast(ac01[r]);
            sX3[(rr + 16) * 132 + c0 + 16] = gelu_fast(ac11[r]);
        }
    }
    __syncthreads();   // B4: X3 ready

    // ---- layer4 (fp32) + decision + flag: 32 rows x 8 lanes ----
    {
        const int row = tid >> 3;              // 0..31
        const int j   = tid & 7;
        float p = 0.0f;
        #pragma unroll
        for (int t = 0; t < 16; ++t)
            p = fmaf(sX3[row * 132 + j + 8 * t], W_l3[j + 8 * t], p);
        p += __shfl_down(p, 4, 8);
        p += __shfl_down(p, 2, 8);
        p += __shfl_down(p, 1, 8);
        if (j == 0) {
            const float prob = 1.0f / (1.0f + expf(-p));
            const float v    = prob * prev_m[row0 + row];
            const float st   = (v > 0.5f) ? 1.0f : 0.0f;
            const float cm   = st + 1e-10f;
            sM[row] = cm;
            mask_out[row0 + row]  = st;
            currm_out[row0 + row] = cm;
            if (fabsf(v - 0.5f) < BAND) {
                const unsigned int slot = atomicAdd(ctr, 1u);
                list[slot] = row0 + row;
            }
        }
    }
    __syncthreads();   // B5: sM ready

    // ---- epilogue: out = input * curr_m (re-read; L3-resident) ----
    #pragma unroll 4
    for (int it = 0; it < 16; ++it) {
        const int c = it * NT + tid;           // 4096 float4 = 32 rows x 128
        const int r = c >> 7;
        const int q = (c & 127) << 2;
        const float m = sM[r];
        const float4 v = *(const float4*)&input[(size_t)(row0 + r) * D0 + q];
        float4 o;
        o.x = v.x * m; o.y = v.y * m; o.z = v.z * m; o.w = v.w * m;
        *(float4*)&out[(size_t)(row0 + r) * D0 + q] = o;
    }
}

// ---------------- pass C: exact fp32 recompute, 2 columns/thread ------------
// (byte-identical to R13's measured fix pass)
__global__ __launch_bounds__(512) void fix_rows(
    const float* __restrict__ input, const float* __restrict__ prev_m,
    const float* __restrict__ WT1, const float* __restrict__ WT2,
    const float* __restrict__ WT3, const float* __restrict__ W_l3,
    const unsigned int* __restrict__ ctr, const int* __restrict__ list,
    float* __restrict__ out, float* __restrict__ mask_out, float* __restrict__ currm_out)
{
    __shared__ float sx[16][512];
    __shared__ float s1[16][512];
    __shared__ float s2[16][256];
    __shared__ float s3[16][128];
    __shared__ float scm[16];
    const int tid = threadIdx.x;
    const int n = (int)*ctr;

    for (int base = blockIdx.x * 16; base < n; base += gridDim.x * 16) {
        int cnt = n - base;
        if (cnt > 16) cnt = 16;
        __syncthreads();                       // protect prev iteration LDS
        #pragma unroll
        for (int g = 0; g < 16; ++g) {
            sx[g][tid] = (g < cnt) ? input[(size_t)list[base + g] * 512 + tid]
                                   : 0.0f;
        }
        __syncthreads();
        // L1: e in {tid&255, +256}; rows g0..g0+7 (g0 = (tid>>8)*8)
        {
            const int e = tid & 255, g0 = (tid >> 8) * 8;
            float a0[8], a1[8];
            #pragma unroll
            for (int g = 0; g < 8; ++g) { a0[g] = 0.0f; a1[g] = 0.0f; }
            #pragma unroll 2
            for (int kq = 0; kq < 128; ++kq) {
                const float u0 = WT1[(kq * 4 + 0) * 512 + e];
                const float u1 = WT1[(kq * 4 + 1) * 512 + e];
                const float u2 = WT1[(kq * 4 + 2) * 512 + e];
                const float u3 = WT1[(kq * 4 + 3) * 512 + e];
                const float v0 = WT1[(kq * 4 + 0) * 512 + e + 256];
                const float v1 = WT1[(kq * 4 + 1) * 512 + e + 256];
                const float v2 = WT1[(kq * 4 + 2) * 512 + e + 256];
                const float v3 = WT1[(kq * 4 + 3) * 512 + e + 256];
                #pragma unroll
                for (int g = 0; g < 8; ++g) {
                    const float4 xv = *(const float4*)&sx[g0 + g][kq * 4];
                    a0[g] = fmaf(xv.x, u0, a0[g]); a0[g] = fmaf(xv.y, u1, a0[g]);
                    a0[g] = fmaf(xv.z, u2, a0[g]); a0[g] = fmaf(xv.w, u3, a0[g]);
                    a1[g] = fmaf(xv.x, v0, a1[g]); a1[g] = fmaf(xv.y, v1, a1[g]);
                    a1[g] = fmaf(xv.z, v2, a1[g]); a1[g] = fmaf(xv.w, v3, a1[g]);
                }
            }
            #pragma unroll
            for (int g = 0; g < 8; ++g) {
                s1[g0 + g][e]       = gelu_exact(a0[g]);
                s1[g0 + g][e + 256] = gelu_exact(a1[g]);
            }
        }
        __syncthreads();
        // L2: e in {tid&127, +128}; rows g0..g0+3 (g0 = (tid>>7)*4)
        {
            const int e = tid & 127, g0 = (tid >> 7) * 4;
            float a0[4], a1[4];
            #pragma unroll
            for (int g = 0; g < 4; ++g) { a0[g] = 0.0f; a1[g] = 0.0f; }
            #pragma unroll 2
            for (int kq = 0; kq < 128; ++kq) {
                const float u0 = WT2[(kq * 4 + 0) * 256 + e];
                const float u1 = WT2[(kq * 4 + 1) * 256 + e];
                const float u2 = WT2[(kq * 4 + 2) * 256 + e];
                const float u3 = WT2[(kq * 4 + 3) * 256 + e];
                const float v0 = WT2[(kq * 4 + 0) * 256 + e + 128];
                const float v1 = WT2[(kq * 4 + 1) * 256 + e + 128];
                const float v2 = WT2[(kq * 4 + 2) * 256 + e + 128];
                const float v3 = WT2[(kq * 4 + 3) * 256 + e + 128];
                #pragma unroll
                for (int g = 0; g < 4; ++g) {
                    const float4 xv = *(const float4*)&s1[g0 + g][kq * 4];
                    a0[g] = fmaf(xv.x, u0, a0[g]); a0[g] = fmaf(xv.y, u1, a0[g]);
                    a0[g] = fmaf(xv.z, u2, a0[g]); a0[g] = fmaf(xv.w, u3, a0[g]);
                    a1[g] = fmaf(xv.x, v0, a1[g]); a1[g] = fmaf(xv.y, v1, a1[g]);
                    a1[g] = fmaf(xv.z, v2, a1[g]); a1[g] = fmaf(xv.w, v3, a1[g]);
                }
            }
            #pragma unroll
            for (int g = 0; g < 4; ++g) {
                s2[g0 + g][e]       = gelu_exact(a0[g]);
                s2[g0 + g][e + 128] = gelu_exact(a1[g]);
            }
        }
        __syncthreads();
        // L3: e in {tid&63, +64}; rows g0..g0+1 (g0 = (tid>>6)*2)
        {
            const int e = tid & 63, g0 = (tid >> 6) * 2;
            float a0[2], a1[2];
            #pragma unroll
            for (int g = 0; g < 2; ++g) { a0[g] = 0.0f; a1[g] = 0.0f; }
            #pragma unroll 2
            for (int kq = 0; kq < 64; ++kq) {
                const float u0 = WT3[(kq * 4 + 0) * 128 + e];
                const float u1 = WT3[(kq * 4 + 1) * 128 + e];
                const float u2 = WT3[(kq * 4 + 2) * 128 + e];
                const float u3 = WT3[(kq * 4 + 3) * 128 + e];
                const float v0 = WT3[(kq * 4 + 0) * 128 + e + 64];
                const float v1 = WT3[(kq * 4 + 1) * 128 + e + 64];
                const float v2 = WT3[(kq * 4 + 2) * 128 + e + 64];
                const float v3 = WT3[(kq * 4 + 3) * 128 + e + 64];
                #pragma unroll
                for (int g = 0; g < 2; ++g) {
                    const float4 xv = *(const float4*)&s2[g0 + g][kq * 4];
                    a0[g] = fmaf(xv.x, u0, a0[g]); a0[g] = fmaf(xv.y, u1, a0[g]);
                    a0[g] = fmaf(xv.z, u2, a0[g]); a0[g] = fmaf(xv.w, u3, a0[g]);
                    a1[g] = fmaf(xv.x, v0, a1[g]); a1[g] = fmaf(xv.y, v1, a1[g]);
                    a1[g] = fmaf(xv.z, v2, a1[g]); a1[g] = fmaf(xv.w, v3, a1[g]);
                }
            }
            #pragma unroll
            for (int g = 0; g < 2; ++g) {
                s3[g0 + g][e]      = gelu_exact(a0[g]);
                s3[g0 + g][e + 64] = gelu_exact(a1[g]);
            }
        }
        __syncthreads();
        // L4 + decision: 16 rows x 16 lanes (tid < 256)
        if (tid < 256) {
            const int g = tid >> 4, j = tid & 15;
            float p = 0.0f;
            #pragma unroll
            for (int t = 0; t < 8; ++t)
                p = fmaf(s3[g][j + 16 * t], W_l3[j + 16 * t], p);
            #pragma unroll
            for (int off = 8; off > 0; off >>= 1)
                p += __shfl_down(p, off, 16);
            if (j == 0 && g < cnt) {
                const int row = list[base + g];
                const float prob = 1.0f / (1.0f + expf(-p));
                const float v    = prob * prev_m[row];
                const float st   = (v > 0.5f) ? 1.0f : 0.0f;
                const float cm   = st + 1e-10f;
                mask_out[row]  = st;
                currm_out[row] = cm;
                scm[g] = cm;
            }
        }
        __syncthreads();
        // rewrite out rows
        for (int idx = tid; idx < cnt * 128; idx += 512) {
            const int g = idx >> 7;
            const int q = (idx & 127) << 2;
            const int row = list[base + g];
            const float cm = scm[g];
            const float4 v = *(const float4*)&input[(size_t)row * 512 + q];
            float4 o;
            o.x = v.x * cm; o.y = v.y * cm; o.z = v.z * cm; o.w = v.w * cm;
            *(float4*)&out[(size_t)row * 512 + q] = o;
        }
    }
}

}  // namespace

extern "C" void kernel_launch(void* const* d_in, const int* in_sizes, int n_in,
                              void* d_out, int out_size, void* d_ws, size_t ws_size,
                              hipStream_t stream) {
    const float* input  = (const float*)d_in[0];
    // d_in[1] = attention_mask: unused by the reference computation
    const float* prev_m = (const float*)d_in[2];
    const float* W_L    = (const float*)d_in[3];
    const float* W_l1   = (const float*)d_in[4];
    const float* W_l2   = (const float*)d_in[5];
    const float* W_l3   = (const float*)d_in[6];

    float* out_p   = (float*)d_out;                  // [R, 512]
    float* mask_p  = out_p + (size_t)R_ROWS * D0;    // [R]
    float* currm_p = mask_p + R_ROWS;                // [R]

    // workspace (bytes): ctr @0, list @1024 (256KB), packed fp16 weights,
    // then fp32 transposed weights for the fix pass.
    char* ws = (char*)d_ws;
    unsigned int* ctr = (unsigned int*)ws;
    int* list = (int*)(ws + 1024);
    char* P1 = ws + 263168;                 // 512 KB
    char* P2 = ws + 787456;                 // 256 KB
    char* P3 = ws + 1049600;                // 64 KB
    float* WT1 = (float*)(ws + 1115136);    // 1 MB
    float* WT2 = (float*)(ws + 2163712);    // 512 KB
    float* WT3 = (float*)(ws + 2688000);    // 128 KB
    // total ws use: 2819072 bytes

    prep_weights<<<1872, 256, 0, stream>>>(W_L, W_l1, W_l2, P1, P2, P3,
                                           WT1, WT2, WT3, ctr);
    mlp_mfma<<<R_ROWS / TM, NT, 0, stream>>>(input, prev_m, W_l3,
                                             P1, P2, P3,
                                             out_p, mask_p, currm_p, ctr, list);
    fix_rows<<<512, 512, 0, stream>>>(input, prev_m, WT1, WT2, WT3, W_l3,
                                      ctr, list, out_p, mask_p, currm_p);
}

// Round 17
// 230.667 us; speedup vs baseline: 1.0497x; 1.0497x over previous
//
#include <hip/hip_runtime.h>
#include <math.h>

// infoFSM mask-scorer MLP — Round 16: revert to R13 (best measured, 236us)
// + ctr-zero folded into prep (R15-validated, -1 launch).
//
// R15 post-mortem (REGRESSION 181us main): 4 independent 256-thr blocks/CU
// ran SLOWER than 2x512 — phase-overlap theory refuted. Campaign score on
// the 167us main plateau: R7 reg-pipelining null, R6/R14 L2-halving null x2,
// R15 block-independence negative. All pipes <35% -> latency-bound in a way
// this 7-barrier fused structure cannot escape at HIP source; the proven
// optimum is R13's TM=32/NT=512 main + 2-col/thread fix.
// This round: R13 kernels byte-identical; only delta = ctr zeroed by prep
// (saves the hipMemsetAsync launch).
// Numerics: fp16 single-term MFMA, BAND=2e-3 (~22sigma), exact fp32 fix.

namespace {

constexpr int R_ROWS = 128 * 512;   // 65536
constexpr int D0 = 512, D1 = 512, D2 = 256, D3 = 128;
constexpr int TM = 32;              // rows per block (pass B)
constexpr int NT = 512;             // 8 waves

typedef _Float16 vhalf8 __attribute__((ext_vector_type(8)));
typedef _Float16 vhalf4 __attribute__((ext_vector_type(4)));
typedef __attribute__((ext_vector_type(16))) float vf16;
typedef __attribute__((ext_vector_type(4)))  float vf4;

// ---------------- helpers ----------------
__device__ __forceinline__ float gelu_exact(float x) {
    return 0.5f * x * (1.0f + erff(x * 0.70710678118654752440f));
}
// A&S 7.1.26 erf: |abs err| <= 1.5e-7 — far below fp16 path error.
__device__ __forceinline__ float gelu_fast(float x) {
    const float s = fabsf(x) * 0.70710678118654752440f;
    const float t = __builtin_amdgcn_rcpf(fmaf(0.3275911f, s, 1.0f));
    float p = fmaf(1.061405429f, t, -1.453152027f);
    p = fmaf(p, t, 1.421413741f);
    p = fmaf(p, t, -0.284496736f);
    p = fmaf(p, t, 0.254829592f);
    p *= t;
    const float e = __builtin_amdgcn_exp2f(s * s * -1.44269504088896341f);
    float er = fmaf(-p, e, 1.0f);             // erf(|x|/sqrt2)
    er = copysignf(er, x);
    return 0.5f * x * (1.0f + er);
}
__device__ __forceinline__ vf16 vzero16() {
    vf16 v;
    #pragma unroll
    for (int i = 0; i < 16; ++i) v[i] = 0.0f;
    return v;
}
__device__ __forceinline__ vf4 vzero4() {
    vf4 v;
    #pragma unroll
    for (int i = 0; i < 4; ++i) v[i] = 0.0f;
    return v;
}

// LDS activation tiles: [row][k] fp16, XOR-swizzle bits 4..6.
__device__ __forceinline__ int swz_off(int row, int colElem, int pitchB) {
    return (row * pitchB + colElem * 2) ^ ((row & 7) << 4);
}
// 32x32 A-fragment read: row = lane&31, k = k0 + (lane>>5)*8
__device__ __forceinline__ vhalf8 ld_act32(const char* base, int lane, int pitchB,
                                           int k0) {
    const int row = lane & 31;
    const int k = k0 + ((lane >> 5) << 3);
    return *(const vhalf8*)(base + swz_off(row, k, pitchB));
}
// 16x16 A-fragment read: row = row0 + lane&15, k = k0 + (lane>>4)*8
__device__ __forceinline__ vhalf8 ld_act16(const char* base, int lane, int pitchB,
                                           int row0, int k0) {
    const int row = row0 + (lane & 15);
    const int k = k0 + ((lane >> 4) << 3);
    return *(const vhalf8*)(base + swz_off(row, k, pitchB));
}
// packed weight fragment: P + blk*1024B + lane*16B
__device__ __forceinline__ vhalf8 ld_pack(const char* __restrict__ P,
                                          int blk, int lane) {
    return *(const vhalf8*)(P + (((size_t)blk) << 10) + (lane << 4));
}
__device__ __forceinline__ void st_hi(char* base, int row, int col, int pitchB, float x) {
    *(_Float16*)(base + swz_off(row, col, pitchB)) = (_Float16)x;
}

#define MFMA32(a, b, c) __builtin_amdgcn_mfma_f32_32x32x16_f16((a), (b), (c), 0, 0, 0)
#define MFMA16(a, b, c) __builtin_amdgcn_mfma_f32_16x16x32_f16((a), (b), (c), 0, 0, 0)

constexpr float BAND = 2e-3f;   // on v = prob*prev_m; ~22x RMS fp16-path err

// ---------------- pass A: prep weights (+ctr zero; pack + transposes) -------
__global__ __launch_bounds__(256) void prep_weights(
    const float* __restrict__ W_L, const float* __restrict__ W_l1,
    const float* __restrict__ W_l2,
    char* __restrict__ P1, char* __restrict__ P2, char* __restrict__ P3,
    float* __restrict__ WT1, float* __restrict__ WT2, float* __restrict__ WT3,
    unsigned int* __restrict__ ctr)
{
    if (blockIdx.x == 0 && threadIdx.x == 0) *ctr = 0;   // replaces memset
    if (blockIdx.x < 208) {
        const int g = blockIdx.x * 256 + threadIdx.x;   // 53248 threads
        const float* src;
        char* dst;
        int e, k, K, blk, lane;
        if (g < 32768) {
            lane = g & 63;
            const int ks = (g >> 6) & 31, nt = g >> 11;
            src = W_L; K = 512; dst = P1;
            e = nt * 32 + (lane & 31);
            k = ks * 16 + ((lane >> 5) << 3);
            blk = nt * 32 + ks;
        } else if (g < 49152) {
            const int h = g - 32768;
            lane = h & 63;
            const int ks = (h >> 6) & 31, nt = h >> 11;
            src = W_l1; K = 512; dst = P2;
            e = nt * 32 + (lane & 31);
            k = ks * 16 + ((lane >> 5) << 3);
            blk = nt * 32 + ks;
        } else {
            const int h = g - 49152;
            lane = h & 63;
            const int ks = (h >> 6) & 7, nt = h >> 9;
            src = W_l2; K = 256; dst = P3;
            e = nt * 16 + (lane & 15);
            k = ks * 32 + ((lane >> 4) << 3);
            blk = nt * 8 + ks;
        }
        const float4 v0 = *(const float4*)&src[(size_t)e * K + k];
        const float4 v1 = *(const float4*)&src[(size_t)e * K + k + 4];
        const float xs[8] = {v0.x, v0.y, v0.z, v0.w, v1.x, v1.y, v1.z, v1.w};
        vhalf8 hv;
        #pragma unroll
        for (int j = 0; j < 8; ++j) hv[j] = (_Float16)xs[j];
        *(vhalf8*)(dst + (((size_t)blk) << 10) + lane * 16) = hv;
    } else {
        const int g = (blockIdx.x - 208) * 256 + threadIdx.x;   // 425984 threads
        if (g < 262144) {
            const int k = g >> 9, e = g & 511;
            WT1[g] = W_L[(size_t)e * 512 + k];
        } else if (g < 393216) {
            const int h = g - 262144;
            const int k = h >> 8, e = h & 255;
            WT2[h] = W_l1[(size_t)e * 512 + k];
        } else {
            const int h = g - 393216;
            const int k = h >> 7, e = h & 127;
            WT3[h] = W_l2[(size_t)e * 256 + k];
        }
    }
}

// ---------------- pass B: fused fp16 MFMA MLP, TM=32, 33.4KB LDS ------------
// (byte-identical to R10/R13's measured 167us kernel)
constexpr int SMEM_BYTES = 33280 + 128;

__global__ __launch_bounds__(NT, 4) void mlp_mfma(
    const float* __restrict__ input, const float* __restrict__ prev_m,
    const float* __restrict__ W_l3,
    const char* __restrict__ P1, const char* __restrict__ P2,
    const char* __restrict__ P3,
    float* __restrict__ out, float* __restrict__ mask_out, float* __restrict__ currm_out,
    unsigned int* __restrict__ ctr, int* __restrict__ list)
{
    __shared__ __attribute__((aligned(16))) char smem[SMEM_BYTES];
    char* A   = smem;                         // then X1, then X2 (overlaid)
    float* sX3 = (float*)(smem + 16384);      // [32][132] f32
    float* sM  = (float*)(smem + 33280);      // [32]

    const int tid  = threadIdx.x;
    const int lane = tid & 63;
    const int wid  = tid >> 6;
    const int row0 = blockIdx.x * TM;

    // ---- stage A: 32 input rows -> fp16, swizzled ----
    #pragma unroll
    for (int i = 0; i < 8; ++i) {
        const int c  = i * NT + tid;           // 0..4095 float4-chunks
        const int r  = c >> 7;                 // 0..31
        const int kq = (c & 127) << 2;
        const float4 v = *(const float4*)&input[(size_t)(row0 + r) * D0 + kq];
        vhalf4 hv = {(_Float16)v.x, (_Float16)v.y, (_Float16)v.z, (_Float16)v.w};
        const int off = (r * 1024 + kq * 2) ^ ((r & 7) << 4);   // 8B-aligned
        *(vhalf4*)(A + off) = hv;
    }
    __syncthreads();   // B1: A staged

    // ---- GEMM1: X1 = gelu(A @ W_L^T), 32x512, K=512, 32x32x16 ----
    vf16 g1a0, g1a1;
    {
        const int nt0 = wid * 2;
        vf16 aE0 = vzero16(), aE1 = vzero16();
        vf16 aO0 = vzero16(), aO1 = vzero16();
        #pragma unroll 2
        for (int ks = 0; ks < 32; ks += 2) {
            {
                const int k0 = ks * 16;
                vhalf8 ah = ld_act32(A, lane, 1024, k0);
                vhalf8 b0 = ld_pack(P1, nt0 * 32 + ks, lane);
                vhalf8 b1 = ld_pack(P1, (nt0 + 1) * 32 + ks, lane);
                aE0 = MFMA32(ah, b0, aE0);
                aE1 = MFMA32(ah, b1, aE1);
            }
            {
                const int k0 = ks * 16 + 16;
                vhalf8 ah = ld_act32(A, lane, 1024, k0);
                vhalf8 b0 = ld_pack(P1, nt0 * 32 + ks + 1, lane);
                vhalf8 b1 = ld_pack(P1, (nt0 + 1) * 32 + ks + 1, lane);
                aO0 = MFMA32(ah, b0, aO0);
                aO1 = MFMA32(ah, b1, aO1);
            }
        }
        g1a0 = aE0 + aO0; g1a1 = aE1 + aO1;
    }
    __syncthreads();   // B2a: all waves done reading A
    {
        const int e0 = wid * 64;
        #pragma unroll
        for (int r = 0; r < 16; ++r) {
            const int rr = (r & 3) + 8 * (r >> 2) + 4 * (lane >> 5);
            st_hi(A, rr, e0 + (lane & 31),      1024, gelu_fast(g1a0[r]));
            st_hi(A, rr, e0 + 32 + (lane & 31), 1024, gelu_fast(g1a1[r]));
        }
    }
    __syncthreads();   // B2b: X1 ready (in A's region)

    // ---- GEMM2: X2 = gelu(X1 @ W_l1^T), 32x256, K=512, 32x32x16 ----
    vf16 g2a;
    {
        vf16 cE = vzero16(), cO = vzero16();
        #pragma unroll 2
        for (int ks = 0; ks < 32; ks += 2) {
            {
                const int k0 = ks * 16;
                vhalf8 ah = ld_act32(A, lane, 1024, k0);
                vhalf8 b  = ld_pack(P2, wid * 32 + ks, lane);
                cE = MFMA32(ah, b, cE);
            }
            {
                const int k0 = ks * 16 + 16;
                vhalf8 ah = ld_act32(A, lane, 1024, k0);
                vhalf8 b  = ld_pack(P2, wid * 32 + ks + 1, lane);
                cO = MFMA32(ah, b, cO);
            }
        }
        g2a = cE + cO;
    }
    __syncthreads();   // B3a: all waves done reading X1
    {
        const int e0 = wid * 32;
        #pragma unroll
        for (int r = 0; r < 16; ++r) {
            const int rr = (r & 3) + 8 * (r >> 2) + 4 * (lane >> 5);
            st_hi(A, rr, e0 + (lane & 31), 512, gelu_fast(g2a[r]));
        }
    }
    __syncthreads();   // B3b: X2 ready (in [0,16K))

    // ---- GEMM3: X3 = gelu(X2 @ W_l2^T), 32x128, K=256, 16x16x32 ----
    {
        const int e0 = wid * 16;               // wave owns n-tile wid
        vf4 a0E = vzero4(), a1E = vzero4();    // m-tiles rows 0..15 / 16..31
        vf4 a0O = vzero4(), a1O = vzero4();
        #pragma unroll 2
        for (int ks = 0; ks < 8; ks += 2) {
            {
                const int k0 = ks * 32;
                vhalf8 b  = ld_pack(P3, wid * 8 + ks, lane);
                vhalf8 a0 = ld_act16(A, lane, 512, 0,  k0);
                vhalf8 a1 = ld_act16(A, lane, 512, 16, k0);
                a0E = MFMA16(a0, b, a0E);
                a1E = MFMA16(a1, b, a1E);
            }
            {
                const int k0 = ks * 32 + 32;
                vhalf8 b  = ld_pack(P3, wid * 8 + ks + 1, lane);
                vhalf8 a0 = ld_act16(A, lane, 512, 0,  k0);
                vhalf8 a1 = ld_act16(A, lane, 512, 16, k0);
                a0O = MFMA16(a0, b, a0O);
                a1O = MFMA16(a1, b, a1O);
            }
        }
        const vf4 ac0 = a0E + a0O;
        const vf4 ac1 = a1E + a1O;
        // X3 at [16K,33K): disjoint from X2 [0,16K); overlays dead X1 upper.
        #pragma unroll
        for (int r = 0; r < 4; ++r) {
            const int rr = ((lane >> 4) << 2) + r;
            sX3[rr * 132 + e0 + (lane & 15)]        = gelu_fast(ac0[r]);
            sX3[(rr + 16) * 132 + e0 + (lane & 15)] = gelu_fast(ac1[r]);
        }
    }
    __syncthreads();   // B4: X3 ready

    // ---- layer4 (fp32) + decision + flag: 32 rows x 16 lanes ----
    {
        const int row = tid >> 4;
        const int j   = tid & 15;
        float p = 0.0f;
        #pragma unroll
        for (int t = 0; t < 8; ++t)
            p = fmaf(sX3[row * 132 + j + 16 * t], W_l3[j + 16 * t], p);
        #pragma unroll
        for (int off = 8; off > 0; off >>= 1)
            p += __shfl_down(p, off, 16);
        if (j == 0) {
            const float prob = 1.0f / (1.0f + expf(-p));
            const float v    = prob * prev_m[row0 + row];
            const float st   = (v > 0.5f) ? 1.0f : 0.0f;
            const float cm   = st + 1e-10f;
            sM[row] = cm;
            mask_out[row0 + row]  = st;
            currm_out[row0 + row] = cm;
            if (fabsf(v - 0.5f) < BAND) {
                const unsigned int slot = atomicAdd(ctr, 1u);
                list[slot] = row0 + row;
            }
        }
    }
    __syncthreads();   // B5: sM ready

    // ---- epilogue: out = input * curr_m (re-read; L3-resident) ----
    #pragma unroll
    for (int it = 0; it < 8; ++it) {
        const int c = it * NT + tid;           // 4096 float4 = 32 rows x 128
        const int r = c >> 7;
        const int q = (c & 127) << 2;
        const float m = sM[r];
        const float4 v = *(const float4*)&input[(size_t)(row0 + r) * D0 + q];
        float4 o;
        o.x = v.x * m; o.y = v.y * m; o.z = v.z * m; o.w = v.w * m;
        *(float4*)&out[(size_t)(row0 + r) * D0 + q] = o;
    }
}

// ---------------- pass C: exact fp32 recompute, 2 columns/thread ------------
// (byte-identical to R13's measured fix pass)
__global__ __launch_bounds__(512) void fix_rows(
    const float* __restrict__ input, const float* __restrict__ prev_m,
    const float* __restrict__ WT1, const float* __restrict__ WT2,
    const float* __restrict__ WT3, const float* __restrict__ W_l3,
    const unsigned int* __restrict__ ctr, const int* __restrict__ list,
    float* __restrict__ out, float* __restrict__ mask_out, float* __restrict__ currm_out)
{
    __shared__ float sx[16][512];
    __shared__ float s1[16][512];
    __shared__ float s2[16][256];
    __shared__ float s3[16][128];
    __shared__ float scm[16];
    const int tid = threadIdx.x;
    const int n = (int)*ctr;

    for (int base = blockIdx.x * 16; base < n; base += gridDim.x * 16) {
        int cnt = n - base;
        if (cnt > 16) cnt = 16;
        __syncthreads();                       // protect prev iteration LDS
        #pragma unroll
        for (int g = 0; g < 16; ++g) {
            sx[g][tid] = (g < cnt) ? input[(size_t)list[base + g] * 512 + tid]
                                   : 0.0f;
        }
        __syncthreads();
        // L1: e in {tid&255, +256}; rows g0..g0+7 (g0 = (tid>>8)*8)
        {
            const int e = tid & 255, g0 = (tid >> 8) * 8;
            float a0[8], a1[8];
            #pragma unroll
            for (int g = 0; g < 8; ++g) { a0[g] = 0.0f; a1[g] = 0.0f; }
            #pragma unroll 2
            for (int kq = 0; kq < 128; ++kq) {
                const float u0 = WT1[(kq * 4 + 0) * 512 + e];
                const float u1 = WT1[(kq * 4 + 1) * 512 + e];
                const float u2 = WT1[(kq * 4 + 2) * 512 + e];
                const float u3 = WT1[(kq * 4 + 3) * 512 + e];
                const float v0 = WT1[(kq * 4 + 0) * 512 + e + 256];
                const float v1 = WT1[(kq * 4 + 1) * 512 + e + 256];
                const float v2 = WT1[(kq * 4 + 2) * 512 + e + 256];
                const float v3 = WT1[(kq * 4 + 3) * 512 + e + 256];
                #pragma unroll
                for (int g = 0; g < 8; ++g) {
                    const float4 xv = *(const float4*)&sx[g0 + g][kq * 4];
                    a0[g] = fmaf(xv.x, u0, a0[g]); a0[g] = fmaf(xv.y, u1, a0[g]);
                    a0[g] = fmaf(xv.z, u2, a0[g]); a0[g] = fmaf(xv.w, u3, a0[g]);
                    a1[g] = fmaf(xv.x, v0, a1[g]); a1[g] = fmaf(xv.y, v1, a1[g]);
                    a1[g] = fmaf(xv.z, v2, a1[g]); a1[g] = fmaf(xv.w, v3, a1[g]);
                }
            }
            #pragma unroll
            for (int g = 0; g < 8; ++g) {
                s1[g0 + g][e]       = gelu_exact(a0[g]);
                s1[g0 + g][e + 256] = gelu_exact(a1[g]);
            }
        }
        __syncthreads();
        // L2: e in {tid&127, +128}; rows g0..g0+3 (g0 = (tid>>7)*4)
        {
            const int e = tid & 127, g0 = (tid >> 7) * 4;
            float a0[4], a1[4];
            #pragma unroll
            for (int g = 0; g < 4; ++g) { a0[g] = 0.0f; a1[g] = 0.0f; }
            #pragma unroll 2
            for (int kq = 0; kq < 128; ++kq) {
                const float u0 = WT2[(kq * 4 + 0) * 256 + e];
                const float u1 = WT2[(kq * 4 + 1) * 256 + e];
                const float u2 = WT2[(kq * 4 + 2) * 256 + e];
                const float u3 = WT2[(kq * 4 + 3) * 256 + e];
                const float v0 = WT2[(kq * 4 + 0) * 256 + e + 128];
                const float v1 = WT2[(kq * 4 + 1) * 256 + e + 128];
                const float v2 = WT2[(kq * 4 + 2) * 256 + e + 128];
                const float v3 = WT2[(kq * 4 + 3) * 256 + e + 128];
                #pragma unroll
                for (int g = 0; g < 4; ++g) {
                    const float4 xv = *(const float4*)&s1[g0 + g][kq * 4];
                    a0[g] = fmaf(xv.x, u0, a0[g]); a0[g] = fmaf(xv.y, u1, a0[g]);
                    a0[g] = fmaf(xv.z, u2, a0[g]); a0[g] = fmaf(xv.w, u3, a0[g]);
                    a1[g] = fmaf(xv.x, v0, a1[g]); a1[g] = fmaf(xv.y, v1, a1[g]);
                    a1[g] = fmaf(xv.z, v2, a1[g]); a1[g] = fmaf(xv.w, v3, a1[g]);
                }
            }
            #pragma unroll
            for (int g = 0; g < 4; ++g) {
                s2[g0 + g][e]       = gelu_exact(a0[g]);
                s2[g0 + g][e + 128] = gelu_exact(a1[g]);
            }
        }
        __syncthreads();
        // L3: e in {tid&63, +64}; rows g0..g0+1 (g0 = (tid>>6)*2)
        {
            const int e = tid & 63, g0 = (tid >> 6) * 2;
            float a0[2], a1[2];
            #pragma unroll
            for (int g = 0; g < 2; ++g) { a0[g] = 0.0f; a1[g] = 0.0f; }
            #pragma unroll 2
            for (int kq = 0; kq < 64; ++kq) {
                const float u0 = WT3[(kq * 4 + 0) * 128 + e];
                const float u1 = WT3[(kq * 4 + 1) * 128 + e];
                const float u2 = WT3[(kq * 4 + 2) * 128 + e];
                const float u3 = WT3[(kq * 4 + 3) * 128 + e];
                const float v0 = WT3[(kq * 4 + 0) * 128 + e + 64];
                const float v1 = WT3[(kq * 4 + 1) * 128 + e + 64];
                const float v2 = WT3[(kq * 4 + 2) * 128 + e + 64];
                const float v3 = WT3[(kq * 4 + 3) * 128 + e + 64];
                #pragma unroll
                for (int g = 0; g < 2; ++g) {
                    const float4 xv = *(const float4*)&s2[g0 + g][kq * 4];
                    a0[g] = fmaf(xv.x, u0, a0[g]); a0[g] = fmaf(xv.y, u1, a0[g]);
                    a0[g] = fmaf(xv.z, u2, a0[g]); a0[g] = fmaf(xv.w, u3, a0[g]);
                    a1[g] = fmaf(xv.x, v0, a1[g]); a1[g] = fmaf(xv.y, v1, a1[g]);
                    a1[g] = fmaf(xv.z, v2, a1[g]); a1[g] = fmaf(xv.w, v3, a1[g]);
                }
            }
            #pragma unroll
            for (int g = 0; g < 2; ++g) {
                s3[g0 + g][e]      = gelu_exact(a0[g]);
                s3[g0 + g][e + 64] = gelu_exact(a1[g]);
            }
        }
        __syncthreads();
        // L4 + decision: 16 rows x 16 lanes (tid < 256)
        if (tid < 256) {
            const int g = tid >> 4, j = tid & 15;
            float p = 0.0f;
            #pragma unroll
            for (int t = 0; t < 8; ++t)
                p = fmaf(s3[g][j + 16 * t], W_l3[j + 16 * t], p);
            #pragma unroll
            for (int off = 8; off > 0; off >>= 1)
                p += __shfl_down(p, off, 16);
            if (j == 0 && g < cnt) {
                const int row = list[base + g];
                const float prob = 1.0f / (1.0f + expf(-p));
                const float v    = prob * prev_m[row];
                const float st   = (v > 0.5f) ? 1.0f : 0.0f;
                const float cm   = st + 1e-10f;
                mask_out[row]  = st;
                currm_out[row] = cm;
                scm[g] = cm;
            }
        }
        __syncthreads();
        // rewrite out rows
        for (int idx = tid; idx < cnt * 128; idx += 512) {
            const int g = idx >> 7;
            const int q = (idx & 127) << 2;
            const int row = list[base + g];
            const float cm = scm[g];
            const float4 v = *(const float4*)&input[(size_t)row * 512 + q];
            float4 o;
            o.x = v.x * cm; o.y = v.y * cm; o.z = v.z * cm; o.w = v.w * cm;
            *(float4*)&out[(size_t)row * 512 + q] = o;
        }
    }
}

}  // namespace

extern "C" void kernel_launch(void* const* d_in, const int* in_sizes, int n_in,
                              void* d_out, int out_size, void* d_ws, size_t ws_size,
                              hipStream_t stream) {
    const float* input  = (const float*)d_in[0];
    // d_in[1] = attention_mask: unused by the reference computation
    const float* prev_m = (const float*)d_in[2];
    const float* W_L    = (const float*)d_in[3];
    const float* W_l1   = (const float*)d_in[4];
    const float* W_l2   = (const float*)d_in[5];
    const float* W_l3   = (const float*)d_in[6];

    float* out_p   = (float*)d_out;                  // [R, 512]
    float* mask_p  = out_p + (size_t)R_ROWS * D0;    // [R]
    float* currm_p = mask_p + R_ROWS;                // [R]

    // workspace (bytes): ctr @0, list @1024 (256KB), packed fp16 weights,
    // then fp32 transposed weights for the fix pass.
    char* ws = (char*)d_ws;
    unsigned int* ctr = (unsigned int*)ws;
    int* list = (int*)(ws + 1024);
    char* P1 = ws + 263168;                 // 512 KB
    char* P2 = ws + 787456;                 // 256 KB
    char* P3 = ws + 1049600;                // 64 KB
    float* WT1 = (float*)(ws + 1115136);    // 1 MB
    float* WT2 = (float*)(ws + 2163712);    // 512 KB
    float* WT3 = (float*)(ws + 2688000);    // 128 KB
    // total ws use: 2819072 bytes

    prep_weights<<<1872, 256, 0, stream>>>(W_L, W_l1, W_l2, P1, P2, P3,
                                           WT1, WT2, WT3, ctr);
    mlp_mfma<<<R_ROWS / TM, NT, 0, stream>>>(input, prev_m, W_l3,
                                             P1, P2, P3,
                                             out_p, mask_p, currm_p, ctr, list);
    fix_rows<<<512, 512, 0, stream>>>(input, prev_m, WT1, WT2, WT3, W_l3,
                                      ctr, list, out_p, mask_p, currm_p);
}